// Round 2
// baseline (471.882 us; speedup 1.0000x reference)
//
#include <hip/hip_runtime.h>
#include <stdint.h>

#define D 64
#define NT 8
#define BLOCK 256
#define TPB 16   // 64-edge tiles per block (4 per wave)
#define ITERS 4

typedef __attribute__((ext_vector_type(8))) short short8;   // 8 bf16
typedef __attribute__((ext_vector_type(4))) float f32x4;

// packed f32x2 -> bf16x2 (RNE)
__device__ __forceinline__ unsigned pkbf(float lo, float hi) {
    unsigned r;
    asm("v_cvt_pk_bf16_f32 %0, %1, %2" : "=v"(r) : "v"(lo), "v"(hi));
    return r;
}

__global__ void __launch_bounds__(BLOCK, 2)
edge_mlp_kernel(const float* __restrict__ ef, const int* __restrict__ types,
                const float* __restrict__ W, const float* __restrict__ Bv,
                float* __restrict__ out, int E)
{
    // W^T, bf16, packed pairs along k: WT[t][col][k/2], XOR-swizzled. 64 KiB.
    __shared__ unsigned WT[NT * 2048];
    __shared__ float BIAS[NT * 68];   // stride 68: trow*68 mod 32 distinct per type

    const int tid = threadIdx.x;

    // ---- Stage: W -> bf16 W^T in LDS (transpose via pair-pack), bias ----
    {
        const int t  = tid >> 5;
        const int k0 = (tid & 31) * 2;
        const float* w0 = W + (size_t)t * (D * D) + (size_t)k0 * D;
#pragma unroll
        for (int c4 = 0; c4 < D; c4 += 4) {
            f32x4 ra = *(const f32x4*)(w0 + c4);
            f32x4 rb = *(const f32x4*)(w0 + D + c4);
#pragma unroll
            for (int j = 0; j < 4; ++j) {
                const int c = c4 + j;
                unsigned idx = (unsigned)(t * 2048 + c * 32 + (k0 >> 1));
                idx ^= (unsigned)((c & 7) << 2);
                WT[idx] = pkbf(ra[j], rb[j]);
            }
        }
#pragma unroll
        for (int q = 0; q < 2; ++q) {
            const int idx = tid + q * 256;
            BIAS[(idx >> 6) * 68 + (idx & 63)] = Bv[idx];
        }
    }
    __syncthreads();

    const int wave = tid >> 6;
    const int lane = tid & 63;
    const int n = lane & 15;   // MFMA col within 16-block / A row m
    const int g = lane >> 4;   // quad index
    const int ntiles = (E + 63) >> 6;
    const int tlast = ntiles - 1;

    const int ti0 = blockIdx.x * TPB + wave * ITERS;

    // ---- prologue: prefetch tile ti0 ----
    f32x4 an[4][4];
    int tln;
    {
        const int pb = min(ti0, tlast) << 6;
        tln = types[min(pb + lane, E - 1)];
#pragma unroll
        for (int mt = 0; mt < 4; ++mt) {
            const int row = min(pb + mt * 16 + n, E - 1);
            const float* rp = ef + (size_t)row * D + g * 8;
            an[mt][0] = *(const f32x4*)(rp);
            an[mt][1] = *(const f32x4*)(rp + 4);
            an[mt][2] = *(const f32x4*)(rp + 32);
            an[mt][3] = *(const f32x4*)(rp + 36);
        }
    }

#pragma unroll
    for (int it = 0; it < ITERS; ++it) {
        const int tcur = ti0 + it;
        if (tcur >= ntiles) break;
        const int tb = tcur << 6;

        // ---- convert current A to bf16 fragments (consumes an) ----
        short8 fa[4][2];
#pragma unroll
        for (int mt = 0; mt < 4; ++mt) {
            union { unsigned u[4]; short8 s; } u0, u1;
            u0.u[0] = pkbf(an[mt][0][0], an[mt][0][1]);
            u0.u[1] = pkbf(an[mt][0][2], an[mt][0][3]);
            u0.u[2] = pkbf(an[mt][1][0], an[mt][1][1]);
            u0.u[3] = pkbf(an[mt][1][2], an[mt][1][3]);
            u1.u[0] = pkbf(an[mt][2][0], an[mt][2][1]);
            u1.u[1] = pkbf(an[mt][2][2], an[mt][2][3]);
            u1.u[2] = pkbf(an[mt][3][0], an[mt][3][1]);
            u1.u[3] = pkbf(an[mt][3][2], an[mt][3][3]);
            fa[mt][0] = u0.s;
            fa[mt][1] = u1.s;
        }
        const int tl = tln;   // keep current types for shfls below

        // ---- issue next tile's loads NOW (overlap with MFMA loop) ----
        {
            const int pb = min(tcur + 1, tlast) << 6;
            tln = types[min(pb + lane, E - 1)];
#pragma unroll
            for (int mt = 0; mt < 4; ++mt) {
                const int row = min(pb + mt * 16 + n, E - 1);
                const float* rp = ef + (size_t)row * D + g * 8;
                an[mt][0] = *(const f32x4*)(rp);
                an[mt][1] = *(const f32x4*)(rp + 4);
                an[mt][2] = *(const f32x4*)(rp + 32);
                an[mt][3] = *(const f32x4*)(rp + 36);
            }
        }

        // type of each A-row this lane owns (row m = n in sub-tile mt)
        int tt[4];
#pragma unroll
        for (int mt = 0; mt < 4; ++mt) tt[mt] = __shfl(tl, mt * 16 + n);

        f32x4 acc[4][4];
#pragma unroll
        for (int mt = 0; mt < 4; ++mt)
#pragma unroll
            for (int nb = 0; nb < 4; ++nb) acc[mt][nb] = (f32x4){0.f, 0.f, 0.f, 0.f};

        // ---- masked-A accumulation over all 8 types ----
        for (int t = 0; t < NT; ++t) {
            short8 bf[2][4];
#pragma unroll
            for (int kb = 0; kb < 2; ++kb)
#pragma unroll
                for (int nb = 0; nb < 4; ++nb) {
                    const int col = nb * 16 + n;
                    unsigned idx = (unsigned)(t * 2048 + col * 32 + kb * 16 + g * 4);
                    idx ^= (unsigned)((col & 7) << 2);
                    bf[kb][nb] = *(const short8*)&WT[idx];   // ds_read_b128
                }
            const short8 z = (short8)0;
#pragma unroll
            for (int mt = 0; mt < 4; ++mt) {
                const bool m = (tt[mt] == t);
                short8 ma0 = m ? fa[mt][0] : z;
                short8 ma1 = m ? fa[mt][1] : z;
#pragma unroll
                for (int nb = 0; nb < 4; ++nb) {
                    acc[mt][nb] = __builtin_amdgcn_mfma_f32_16x16x32_bf16(ma0, bf[0][nb], acc[mt][nb], 0, 0, 0);
                    acc[mt][nb] = __builtin_amdgcn_mfma_f32_16x16x32_bf16(ma1, bf[1][nb], acc[mt][nb], 0, 0, 0);
                }
            }
        }

        // ---- epilogue: bias + ReLU, streaming nontemporal stores ----
#pragma unroll
        for (int mt = 0; mt < 4; ++mt) {
#pragma unroll
            for (int r = 0; r < 4; ++r) {
                const int lrow = mt * 16 + g * 4 + r;   // C/D: col=lane&15, row=g*4+r
                const int row  = tb + lrow;
                const int trow = __shfl(tl, lrow);
                if (row < E) {
                    float* orow = out + (size_t)row * D;
#pragma unroll
                    for (int nb = 0; nb < 4; ++nb) {
                        float v = acc[mt][nb][r] + BIAS[trow * 68 + nb * 16 + n];
                        v = v > 0.f ? v : 0.f;
                        __builtin_nontemporal_store(v, &orow[nb * 16 + n]);
                    }
                }
            }
        }
    }
}

extern "C" void kernel_launch(void* const* d_in, const int* in_sizes, int n_in,
                              void* d_out, int out_size, void* d_ws, size_t ws_size,
                              hipStream_t stream) {
    const float* ef    = (const float*)d_in[0];
    const int*   types = (const int*)d_in[1];
    const float* W     = (const float*)d_in[2];
    const float* Bv    = (const float*)d_in[3];
    float* out = (float*)d_out;
    const int E = in_sizes[1];
    const int ntiles = (E + 63) / 64;
    const int grid = (ntiles + TPB - 1) / TPB;
    hipLaunchKernelGGL(edge_mlp_kernel, dim3(grid), dim3(BLOCK), 0, stream,
                       ef, types, W, Bv, out, E);
}